// Round 15
// baseline (96.410 us; speedup 1.0000x reference)
//
#include <hip/hip_runtime.h>

// Capsule routing, MI355X. B=2048, I=64, O=32, DI=DO=16, 3 iters.
// R15: A-phase moved to MFMA (v_mfma_f32_16x16x32_bf16), exact-split bf16:
//   W = W_hi + W_lo, x = x_hi + x_lo (trunc-split, residual exact to 2^-16).
//   Per (i, b-group): acc = mfma(Wlo,[xhi|xlo], mfma(Whi... wait order:
//   acc = mfma(Whi,B, mfma(Wlo,B,0)) = (Whi+Wlo)(xhi+xlo) = W*x.
//   A-frag (dup): A[d][k] = W_pl[d][k mod 16]; B[k][n=b]: k<16 xhi, k>=16 xlo.
// Wave w owns i in [8w, 8w+8): whi/wlo frags = 64 VGPR; 2 MFMA + 1 b128
//   B-frag read + 4 b32 p-stores per i.
// x_t LDS layout (bf16): unit(i,b,eo,pl) 16B at i*512 + ((b*4+eo*2+pl)^((i>>3)&7))*16
//   -> reader conflict-free (b-bit3 broadcast + 4 quads), writer b128 sweeps
//   8 quads via (i>>3) XOR (strided-8 phase model, R11/R12-verified).
// p layout: word = (b*16+d)*64 + 4*((i>>2)^g) + (i&3), g = (d&7)^(b&7)^((2*(d>>2))&7)
//   writer (MFMA lanes, fixed i) 4-way b32; reader slots (4qB+jj)^g, 2-way.
// B-phase/softmax/out = R14 verbatim. W' = rw+ns precomputed (wsum kernel).
// Straight-line, constant-indexed (R7 lesson); no min-wave forcing (R2/R5).

#define THREADS 512

typedef __attribute__((ext_vector_type(8))) short bf16x8;
typedef __attribute__((ext_vector_type(4))) float f32x4;

__device__ __forceinline__ unsigned hi_bits(float v) {
    return __float_as_uint(v) & 0xFFFF0000u;
}
__device__ __forceinline__ unsigned lo_u(float v) {
    return __float_as_uint(v - __uint_as_float(hi_bits(v)));
}

__global__ __launch_bounds__(256) void wsum_kernel(
    const float* __restrict__ rw, const float* __restrict__ ns,
    float* __restrict__ w2)
{
    const int i = blockIdx.x * 256 + threadIdx.x;   // 131072 float4s
    const float4 a = reinterpret_cast<const float4*>(rw)[i];
    const float4 n = reinterpret_cast<const float4*>(ns)[i];
    float4 r;
    r.x = a.x + n.x;  r.y = a.y + n.y;  r.z = a.z + n.z;  r.w = a.w + n.w;
    reinterpret_cast<float4*>(w2)[i] = r;
}

template <bool PRE>
__global__ __launch_bounds__(THREADS) void routing_kernel(
    const float* __restrict__ x,    // (B, DI, I) = (2048,16,64)
    const float* __restrict__ rw,   // PRE ? W' : rw   (O,I,DO,DI)
    const float* __restrict__ ns,   // unused if PRE
    float* __restrict__ out)        // (1, O, B, DO)
{
    extern __shared__ float lds[];  // [0,8192) p f32; bytes [32768,65536) x_t bf16

    const int tid  = threadIdx.x;
    const int w    = tid >> 6;      // wave 0..7
    const int lane = tid & 63;

    const int o  = blockIdx.x >> 5;   // o-major
    const int bc = blockIdx.x & 31;   // 64-b chunk
    const int bbase = bc * 64;

    // ---- W fragments: wave w owns i = 8w+t. lane: d=lane&15, e-octet ----
    bf16x8 whi[8], wlo[8];
    {
        const int dW  = lane & 15;
        const int eoW = (lane >> 4) & 1;
        const int wb  = ((o * 64 + 8 * w) * 16 + dW) * 16 + eoW * 8;
        #pragma unroll
        for (int t = 0; t < 8; ++t) {
            float4 f0 = *reinterpret_cast<const float4*>(rw + wb + t * 256);
            float4 f1 = *reinterpret_cast<const float4*>(rw + wb + t * 256 + 4);
            if (!PRE) {
                const float4 n0 = *reinterpret_cast<const float4*>(ns + wb + t * 256);
                const float4 n1 = *reinterpret_cast<const float4*>(ns + wb + t * 256 + 4);
                f0.x += n0.x; f0.y += n0.y; f0.z += n0.z; f0.w += n0.w;
                f1.x += n1.x; f1.y += n1.y; f1.z += n1.z; f1.w += n1.w;
            }
            whi[t][0] = (short)(__float_as_uint(f0.x) >> 16);
            whi[t][1] = (short)(__float_as_uint(f0.y) >> 16);
            whi[t][2] = (short)(__float_as_uint(f0.z) >> 16);
            whi[t][3] = (short)(__float_as_uint(f0.w) >> 16);
            whi[t][4] = (short)(__float_as_uint(f1.x) >> 16);
            whi[t][5] = (short)(__float_as_uint(f1.y) >> 16);
            whi[t][6] = (short)(__float_as_uint(f1.z) >> 16);
            whi[t][7] = (short)(__float_as_uint(f1.w) >> 16);
            wlo[t][0] = (short)(lo_u(f0.x) >> 16);
            wlo[t][1] = (short)(lo_u(f0.y) >> 16);
            wlo[t][2] = (short)(lo_u(f0.z) >> 16);
            wlo[t][3] = (short)(lo_u(f0.w) >> 16);
            wlo[t][4] = (short)(lo_u(f1.x) >> 16);
            wlo[t][5] = (short)(lo_u(f1.y) >> 16);
            wlo[t][6] = (short)(lo_u(f1.z) >> 16);
            wlo[t][7] = (short)(lo_u(f1.w) >> 16);
        }
    }

    // ---- x_t addresses ----
    const int ridx = ((lane & 7) << 2) | (((lane >> 4) & 1) << 1) | (lane >> 5);
    const char* xt_rd = reinterpret_cast<const char*>(lds) + 32768
                      + w * 4096 + ((ridx ^ (w & 7)) << 4);
    const int kskew = (lane >> 3) & 7;
    char* xt_wr = reinterpret_cast<char*>(lds) + 32768 + lane * 512;
    const int ow00 = ((w * 4 + 0) ^ kskew) << 4;   // eo0, hi
    const int ow01 = ((w * 4 + 1) ^ kskew) << 4;   // eo0, lo
    const int ow10 = ((w * 4 + 2) ^ kskew) << 4;   // eo1, hi
    const int ow11 = ((w * 4 + 3) ^ kskew) << 4;   // eo1, lo

    // ---- p store addressing (MFMA out): b=lane&15 (<8 active), dq=lane>>4 ----
    const int bA  = lane & 15;
    const int dqA = lane >> 4;
    const bool act = (lane & 8) == 0;
    const int g0 = (4 * (dqA & 1) + 0) ^ (bA & 7) ^ ((2 * dqA) & 7);
    const int g1 = (4 * (dqA & 1) + 1) ^ (bA & 7) ^ ((2 * dqA) & 7);
    const int g2 = (4 * (dqA & 1) + 2) ^ (bA & 7) ^ ((2 * dqA) & 7);
    const int g3 = (4 * (dqA & 1) + 3) ^ (bA & 7) ^ ((2 * dqA) & 7);
    float* prow0 = lds + (bA * 16 + 4 * dqA + 0) * 64;
    float* prow1 = lds + (bA * 16 + 4 * dqA + 1) * 64;
    float* prow2 = lds + (bA * 16 + 4 * dqA + 2) * 64;
    float* prow3 = lds + (bA * 16 + 4 * dqA + 3) * 64;
    const int w00 = 4 * ((2 * w + 0) ^ g0), w01 = 4 * ((2 * w + 1) ^ g0);
    const int w10 = 4 * ((2 * w + 0) ^ g1), w11 = 4 * ((2 * w + 1) ^ g1);
    const int w20 = 4 * ((2 * w + 0) ^ g2), w21 = 4 * ((2 * w + 1) ^ g2);
    const int w30 = 4 * ((2 * w + 0) ^ g3), w31 = 4 * ((2 * w + 1) ^ g3);

    // ---- B-phase p reads (R14 + g XOR) ----
    const int qB = lane >> 4;
    const int dB = lane & 15;
    const int gR = (dB & 7) ^ (w & 7) ^ ((2 * (dB >> 2)) & 7);
    const float4* prbase = reinterpret_cast<const float4*>(lds) + (w * 16 + dB) * 16;
    const float4* pr0 = prbase + ((4 * qB + 0) ^ gR);
    const float4* pr1 = prbase + ((4 * qB + 1) ^ gR);
    const float4* pr2 = prbase + ((4 * qB + 2) ^ gR);
    const float4* pr3 = prbase + ((4 * qB + 3) ^ gR);

    const int outbase = (o * 2048 + bbase + w) * 16 + dB;

    // ---- staging helper data: thread (b=w, i=lane), e=0..15 ----
    const float* xsrc = x + (bbase + w) * 1024 + lane;  // + s*8*1024 per s

    // ---- prologue: stage tile 0 ----
    {
        float v[16];
        #pragma unroll
        for (int e = 0; e < 16; ++e) v[e] = xsrc[e * 64];
        unsigned h0 = (__float_as_uint(v[0]) >> 16) | hi_bits(v[1]);
        unsigned h1 = (__float_as_uint(v[2]) >> 16) | hi_bits(v[3]);
        unsigned h2 = (__float_as_uint(v[4]) >> 16) | hi_bits(v[5]);
        unsigned h3 = (__float_as_uint(v[6]) >> 16) | hi_bits(v[7]);
        unsigned h4 = (__float_as_uint(v[8]) >> 16) | hi_bits(v[9]);
        unsigned h5 = (__float_as_uint(v[10]) >> 16) | hi_bits(v[11]);
        unsigned h6 = (__float_as_uint(v[12]) >> 16) | hi_bits(v[13]);
        unsigned h7 = (__float_as_uint(v[14]) >> 16) | hi_bits(v[15]);
        unsigned l0 = (lo_u(v[0]) >> 16) | (lo_u(v[1]) & 0xFFFF0000u);
        unsigned l1 = (lo_u(v[2]) >> 16) | (lo_u(v[3]) & 0xFFFF0000u);
        unsigned l2 = (lo_u(v[4]) >> 16) | (lo_u(v[5]) & 0xFFFF0000u);
        unsigned l3 = (lo_u(v[6]) >> 16) | (lo_u(v[7]) & 0xFFFF0000u);
        unsigned l4 = (lo_u(v[8]) >> 16) | (lo_u(v[9]) & 0xFFFF0000u);
        unsigned l5 = (lo_u(v[10]) >> 16) | (lo_u(v[11]) & 0xFFFF0000u);
        unsigned l6 = (lo_u(v[12]) >> 16) | (lo_u(v[13]) & 0xFFFF0000u);
        unsigned l7 = (lo_u(v[14]) >> 16) | (lo_u(v[15]) & 0xFFFF0000u);
        *reinterpret_cast<uint4*>(xt_wr + ow00) = make_uint4(h0, h1, h2, h3);
        *reinterpret_cast<uint4*>(xt_wr + ow01) = make_uint4(l0, l1, l2, l3);
        *reinterpret_cast<uint4*>(xt_wr + ow10) = make_uint4(h4, h5, h6, h7);
        *reinterpret_cast<uint4*>(xt_wr + ow11) = make_uint4(l4, l5, l6, l7);
    }
    __syncthreads();                // x_t(0) ready

    #pragma unroll
    for (int s = 0; s < 8; ++s) {
        // ---- A-phase: MFMA per i = 8w+t ----
        #pragma unroll
        for (int t = 0; t < 8; ++t) {
            const bf16x8 bf = *reinterpret_cast<const bf16x8*>(xt_rd + t * 512);
            f32x4 acc = {0.f, 0.f, 0.f, 0.f};
            acc = __builtin_amdgcn_mfma_f32_16x16x32_bf16(wlo[t], bf, acc, 0, 0, 0);
            acc = __builtin_amdgcn_mfma_f32_16x16x32_bf16(whi[t], bf, acc, 0, 0, 0);
            if (act) {
                const int m = t & 3;
                prow0[((t >> 2) ? w01 : w00) + m] = acc[0];
                prow1[((t >> 2) ? w11 : w10) + m] = acc[1];
                prow2[((t >> 2) ? w21 : w20) + m] = acc[2];
                prow3[((t >> 2) ? w31 : w30) + m] = acc[3];
            }
        }
        __syncthreads();            // p ready; x_t consumed

        // ---- B-read: p[16] ----
        float p[16];
        {
            const float4 v0 = *pr0, v1 = *pr1, v2 = *pr2, v3 = *pr3;
            p[0]=v0.x; p[1]=v0.y; p[2]=v0.z; p[3]=v0.w;
            p[4]=v1.x; p[5]=v1.y; p[6]=v1.z; p[7]=v1.w;
            p[8]=v2.x; p[9]=v2.y; p[10]=v2.z; p[11]=v2.w;
            p[12]=v3.x; p[13]=v3.y; p[14]=v3.z; p[15]=v3.w;
        }

        // ---- T14 issue-early: next tile e=0..7 ----
        float se[8];
        if (s < 7) {
            const float* xs = xsrc + (s + 1) * 8192;
            se[0] = xs[0];   se[1] = xs[64];  se[2] = xs[128]; se[3] = xs[192];
            se[4] = xs[256]; se[5] = xs[320]; se[6] = xs[384]; se[7] = xs[448];
        }

        // ---- routing iterations (R14 verbatim) ----
        float t0 = (p[0]+p[1]) + (p[2]+p[3]);
        float t1 = (p[4]+p[5]) + (p[6]+p[7]);
        float t2 = (p[8]+p[9]) + (p[10]+p[11]);
        float t3 = (p[12]+p[13]) + (p[14]+p[15]);
        float part = (t0 + t1) + (t2 + t3);
        part += __shfl_xor(part, 16);
        part += __shfl_xor(part, 32);
        float sv = part * (1.0f / 64.0f);

        float sn = sv * sv;
        sn += __shfl_xor(sn, 1); sn += __shfl_xor(sn, 2);
        sn += __shfl_xor(sn, 4); sn += __shfl_xor(sn, 8);
        float factor = __builtin_amdgcn_sqrtf(sn)
                     * __builtin_amdgcn_rcpf(1.0f + sn);
        float Vsum = sv * factor;

        #pragma unroll
        for (int it = 0; it < 2; ++it) {
            const float c = Vsum * 1.44269504089f;
            float e0, e1, e2, e3;
            float dd0, dd1, dd2, dd3, nn0, nn1, nn2, nn3;
            e0 = __builtin_amdgcn_exp2f(p[0] * c);
            e1 = __builtin_amdgcn_exp2f(p[1] * c);
            e2 = __builtin_amdgcn_exp2f(p[2] * c);
            e3 = __builtin_amdgcn_exp2f(p[3] * c);
            dd0 = e0; dd1 = e1; dd2 = e2; dd3 = e3;
            nn0 = e0 * p[0]; nn1 = e1 * p[1]; nn2 = e2 * p[2]; nn3 = e3 * p[3];
            e0 = __builtin_amdgcn_exp2f(p[4] * c);
            e1 = __builtin_amdgcn_exp2f(p[5] * c);
            e2 = __builtin_amdgcn_exp2f(p[6] * c);
            e3 = __builtin_amdgcn_exp2f(p[7] * c);
            dd0 += e0; dd1 += e1; dd2 += e2; dd3 += e3;
            nn0 = fmaf(e0, p[4], nn0); nn1 = fmaf(e1, p[5], nn1);
            nn2 = fmaf(e2, p[6], nn2); nn3 = fmaf(e3, p[7], nn3);
            e0 = __builtin_amdgcn_exp2f(p[8] * c);
            e1 = __builtin_amdgcn_exp2f(p[9] * c);
            e2 = __builtin_amdgcn_exp2f(p[10] * c);
            e3 = __builtin_amdgcn_exp2f(p[11] * c);
            dd0 += e0; dd1 += e1; dd2 += e2; dd3 += e3;
            nn0 = fmaf(e0, p[8], nn0);  nn1 = fmaf(e1, p[9], nn1);
            nn2 = fmaf(e2, p[10], nn2); nn3 = fmaf(e3, p[11], nn3);
            e0 = __builtin_amdgcn_exp2f(p[12] * c);
            e1 = __builtin_amdgcn_exp2f(p[13] * c);
            e2 = __builtin_amdgcn_exp2f(p[14] * c);
            e3 = __builtin_amdgcn_exp2f(p[15] * c);
            dd0 += e0; dd1 += e1; dd2 += e2; dd3 += e3;
            nn0 = fmaf(e0, p[12], nn0); nn1 = fmaf(e1, p[13], nn1);
            nn2 = fmaf(e2, p[14], nn2); nn3 = fmaf(e3, p[15], nn3);

            float den = (dd0 + dd1) + (dd2 + dd3);
            float num = (nn0 + nn1) + (nn2 + nn3);
            den += __shfl_xor(den, 16); den += __shfl_xor(den, 32);
            num += __shfl_xor(num, 16); num += __shfl_xor(num, 32);
            sv = num * __builtin_amdgcn_rcpf(den);
            sn = sv * sv;
            sn += __shfl_xor(sn, 1); sn += __shfl_xor(sn, 2);
            sn += __shfl_xor(sn, 4); sn += __shfl_xor(sn, 8);
            factor = __builtin_amdgcn_sqrtf(sn)
                   * __builtin_amdgcn_rcpf(1.0f + sn);
            Vsum += sv * factor;
        }

        if (qB == 0)
            out[outbase + s * 128] = sv * factor;

        // ---- write-late: finish next tile (e=8..15), cvt, store x_t ----
        if (s < 7) {
            const float* xs = xsrc + (s + 1) * 8192;
            float sl[8];
            sl[0] = xs[512]; sl[1] = xs[576]; sl[2] = xs[640]; sl[3] = xs[704];
            sl[4] = xs[768]; sl[5] = xs[832]; sl[6] = xs[896]; sl[7] = xs[960];
            unsigned h0 = (__float_as_uint(se[0]) >> 16) | hi_bits(se[1]);
            unsigned h1 = (__float_as_uint(se[2]) >> 16) | hi_bits(se[3]);
            unsigned h2 = (__float_as_uint(se[4]) >> 16) | hi_bits(se[5]);
            unsigned h3 = (__float_as_uint(se[6]) >> 16) | hi_bits(se[7]);
            unsigned l0 = (lo_u(se[0]) >> 16) | (lo_u(se[1]) & 0xFFFF0000u);
            unsigned l1 = (lo_u(se[2]) >> 16) | (lo_u(se[3]) & 0xFFFF0000u);
            unsigned l2 = (lo_u(se[4]) >> 16) | (lo_u(se[5]) & 0xFFFF0000u);
            unsigned l3 = (lo_u(se[6]) >> 16) | (lo_u(se[7]) & 0xFFFF0000u);
            unsigned h4 = (__float_as_uint(sl[0]) >> 16) | hi_bits(sl[1]);
            unsigned h5 = (__float_as_uint(sl[2]) >> 16) | hi_bits(sl[3]);
            unsigned h6 = (__float_as_uint(sl[4]) >> 16) | hi_bits(sl[5]);
            unsigned h7 = (__float_as_uint(sl[6]) >> 16) | hi_bits(sl[7]);
            unsigned l4 = (lo_u(sl[0]) >> 16) | (lo_u(sl[1]) & 0xFFFF0000u);
            unsigned l5 = (lo_u(sl[2]) >> 16) | (lo_u(sl[3]) & 0xFFFF0000u);
            unsigned l6 = (lo_u(sl[4]) >> 16) | (lo_u(sl[5]) & 0xFFFF0000u);
            unsigned l7 = (lo_u(sl[6]) >> 16) | (lo_u(sl[7]) & 0xFFFF0000u);
            *reinterpret_cast<uint4*>(xt_wr + ow00) = make_uint4(h0, h1, h2, h3);
            *reinterpret_cast<uint4*>(xt_wr + ow01) = make_uint4(l0, l1, l2, l3);
            *reinterpret_cast<uint4*>(xt_wr + ow10) = make_uint4(h4, h5, h6, h7);
            *reinterpret_cast<uint4*>(xt_wr + ow11) = make_uint4(l4, l5, l6, l7);
        }
        __syncthreads();            // p consumed & x_t(s+1) ready
    }
}

extern "C" void kernel_launch(void* const* d_in, const int* in_sizes, int n_in,
                              void* d_out, int out_size, void* d_ws, size_t ws_size,
                              hipStream_t stream) {
    const float* x  = (const float*)d_in[0];
    const float* rw = (const float*)d_in[1];
    const float* ns = (const float*)d_in[2];
    float* out = (float*)d_out;
    (void)in_sizes; (void)n_in; (void)out_size;

    const int grid = 32 * 32;       // blockIdx = o*32 + bc (64 b per block)
    const size_t w2_bytes = 32u * 64u * 16u * 16u * sizeof(float);  // 2 MB

    if (ws_size >= w2_bytes) {
        float* w2 = (float*)d_ws;
        wsum_kernel<<<512, 256, 0, stream>>>(rw, ns, w2);
        routing_kernel<true><<<grid, THREADS, 65536, stream>>>(x, w2, ns, out);
    } else {
        routing_kernel<false><<<grid, THREADS, 65536, stream>>>(x, rw, ns, out);
    }
}